// Round 7
// baseline (1493.016 us; speedup 1.0000x reference)
//
#include <hip/hip_runtime.h>
#include <hip/hip_bf16.h>
#include <math.h>

// Problem constants
#define CC    256      // channels
#define RR    256      // token bank size
#define HWV   16384    // H*W
#define NPIX  131072   // B*H*W
#define COUT  256
#define PT    64       // pixels per block (k1)

typedef float f4 __attribute__((ext_vector_type(4)));
typedef float f32x4 __attribute__((ext_vector_type(4)));
typedef short bf16x8 __attribute__((ext_vector_type(8)));  // 8 bf16 = 4 VGPRs (guide §3)
typedef short s16x4 __attribute__((ext_vector_type(4)));   // 8B
typedef unsigned short u16;

__device__ __forceinline__ u16 f2bf(float x) {
    __hip_bfloat16 h = __float2bfloat16(x);      // RNE
    return *reinterpret_cast<u16*>(&h);
}
__device__ __forceinline__ float bf2f(u16 u) {
    __hip_bfloat16 h = *reinterpret_cast<__hip_bfloat16*>(&u);
    return __bfloat162float(h);
}

// ---------------- kM: precompute bf16 operand matrices + zero BN accumulators
//  Tbf[r][c]   = bf16(t_items[r][c])                       (A of cue GEMM)
//  Acat[o][k]  = [W1 | M],  M[o][r] = sum_c W2[o][c]*T[r][c]; split hi/lo bf16
__global__ void kM(const float* __restrict__ w_out, const float* __restrict__ t_items,
                   u16* __restrict__ Tbf, u16* __restrict__ Ahi, u16* __restrict__ Alo,
                   float* __restrict__ gsum, float* __restrict__ gss) {
    __shared__ float wl[CC];
    const int o = blockIdx.x;
    const int t = threadIdx.x;           // 256 threads
    if (t == 0) { gsum[o] = 0.0f; gss[o] = 0.0f; }
    wl[t] = w_out[o * 512 + 256 + t];    // W2 row o
    // T row o -> bf16
    Tbf[o * 256 + t] = f2bf(t_items[o * 256 + t]);
    // W1 part of Acat, hi/lo split
    float w1 = w_out[o * 512 + t];
    u16 h1 = f2bf(w1);
    Ahi[o * 512 + t] = h1;
    Alo[o * 512 + t] = f2bf(w1 - bf2f(h1));
    __syncthreads();
    // M[o][t] = dot(W2[o,:], T[t,:]) in fp32, then hi/lo split
    const f4* tr = (const f4*)(t_items + t * CC);
    float acc = 0.0f;
    #pragma unroll
    for (int c4 = 0; c4 < 64; c4++) {
        f4 v = tr[c4];
        acc = fmaf(wl[c4*4+0], v[0], acc);
        acc = fmaf(wl[c4*4+1], v[1], acc);
        acc = fmaf(wl[c4*4+2], v[2], acc);
        acc = fmaf(wl[c4*4+3], v[3], acc);
    }
    u16 h2 = f2bf(acc);
    Ahi[o * 512 + 256 + t] = h2;
    Alo[o * 512 + 256 + t] = f2bf(acc - bf2f(h2));
}

// ---------------- k1: MFMA-fused  normalize -> cue -> softmax -> y = [W1|M]@[qhat;attn]
// 64 pixels/block, 4 waves; wave w owns pixels w*16..w*16+15.
// LDS: qhatT + attnT, bf16 [64][256], XOR-swizzled (u16 idx ^= (p&7)<<3) -> 65.5KB, 2 blocks/CU.
// MFMA 16x16x32_bf16: A lane holds A[l&15][(l>>4)*8+i]; B lane holds B[(l>>4)*8+i][l&15];
// C/D: col=lane&15, row=(lane>>4)*4+reg  (guide §3, m89-verified).
__global__ __launch_bounds__(256, 2)
void k1(const float* __restrict__ query, const u16* __restrict__ Tbf,
        const u16* __restrict__ Ahi, const u16* __restrict__ Alo,
        float* __restrict__ out, float* __restrict__ gsum, float* __restrict__ gss) {
    __shared__ u16 qh[PT * 256];    // qhatT [p][c], swizzled, 32KB
    __shared__ u16 at[PT * 256];    // attnT [p][r], swizzled, 32KB
    __shared__ float nrm[4][PT];
    __shared__ float scl[PT];

    const int t    = threadIdx.x;
    const int l    = t & 63;
    const int w    = t >> 6;          // wave 0..3
    const int pix0 = blockIdx.x * PT;
    const int b    = pix0 >> 14;
    const int hw0  = pix0 & (HWV - 1);
    const int qbase = ((b * CC) << 14) + hw0;

    // ---- Pass A: per-pixel L2 norm; keep this thread's 64 q values in regs
    const int p  = t & 63;            // pixel within tile
    const int ch = t >> 6;            // c-chunk (64 channels each)
    float q[64];
    {
        float ss = 0.0f;
        #pragma unroll
        for (int j = 0; j < 64; j++) {
            q[j] = query[qbase + (ch * 64 + j) * HWV + p];
            ss = fmaf(q[j], q[j], ss);
        }
        nrm[ch][p] = ss;
    }
    __syncthreads();
    if (t < 64) {
        float tot = nrm[0][t] + nrm[1][t] + nrm[2][t] + nrm[3][t];
        scl[t] = 1.0f / fmaxf(sqrtf(tot), 1e-12f);
    }
    __syncthreads();
    // ---- Pass B: qhatT -> LDS as bf16, swizzled
    {
        float s = scl[p];
        #pragma unroll
        for (int g = 0; g < 8; g++) {
            u16 pk[8];
            #pragma unroll
            for (int i = 0; i < 8; i++) pk[i] = f2bf(q[g * 8 + i] * s);
            int c0 = ch * 64 + g * 8;
            int idx = p * 256 + (c0 ^ ((p & 7) << 3));
            *reinterpret_cast<bf16x8*>(&qh[idx]) = *reinterpret_cast<bf16x8*>(pk);
        }
    }
    __syncthreads();

    const int ln  = l & 15;           // n-index within tile (pixel / col)
    const int lh  = l >> 4;           // k-subblock / row-group
    const int p0w = w * 16;
    const int pp  = p0w + ln;         // this lane's pixel
    const int swz = (pp & 7) << 3;

    // ---- cue GEMM: C[r][p] = T · qhatT   (16 r-tiles x 8 k-steps)
    f32x4 acc[16];
    #pragma unroll
    for (int i = 0; i < 16; i++) acc[i] = f32x4{0.f, 0.f, 0.f, 0.f};
    #pragma unroll
    for (int k = 0; k < 8; k++) {
        const int c0 = k * 32 + lh * 8;
        bf16x8 bq = *reinterpret_cast<const bf16x8*>(&qh[pp * 256 + (c0 ^ swz)]);
        #pragma unroll
        for (int i = 0; i < 16; i++) {
            bf16x8 av = *reinterpret_cast<const bf16x8*>(&Tbf[(i * 16 + ln) * 256 + c0]);
            acc[i] = __builtin_amdgcn_mfma_f32_16x16x32_bf16(av, bq, acc[i], 0, 0, 0);
        }
    }

    // ---- softmax over r, fully in-register (lane holds 64 r-values of pixel pp)
    {
        float mx = -1e30f;
        #pragma unroll
        for (int i = 0; i < 16; i++)
            mx = fmaxf(mx, fmaxf(fmaxf(acc[i][0], acc[i][1]), fmaxf(acc[i][2], acc[i][3])));
        mx = fmaxf(mx, __shfl_xor(mx, 16));
        mx = fmaxf(mx, __shfl_xor(mx, 32));
        float sm = 0.0f;
        #pragma unroll
        for (int i = 0; i < 16; i++) {
            #pragma unroll
            for (int r = 0; r < 4; r++) { float e = __expf(acc[i][r] - mx); acc[i][r] = e; sm += e; }
        }
        sm += __shfl_xor(sm, 16);
        sm += __shfl_xor(sm, 32);
        float inv = 1.0f / sm;
        // attnT -> LDS (wave-local rows; 4 consecutive r per (tile,lane) = 8B write)
        #pragma unroll
        for (int i = 0; i < 16; i++) {
            u16 pk[4];
            #pragma unroll
            for (int r = 0; r < 4; r++) pk[r] = f2bf(acc[i][r] * inv);
            int c0 = i * 16 + lh * 4;
            int idx = pp * 256 + (c0 ^ swz);
            *reinterpret_cast<s16x4*>(&at[idx]) = *reinterpret_cast<s16x4*>(pk);
        }
    }
    // no __syncthreads needed: attnT rows are wave-local (write & read same wave)

    // ---- y GEMM: y[o][p] = [W1|M]_hi@[qhat;attn] + [W1|M]_lo@[qhat;attn]  (K=512)
    f32x4 yac[16];
    #pragma unroll
    for (int i = 0; i < 16; i++) yac[i] = f32x4{0.f, 0.f, 0.f, 0.f};
    #pragma unroll
    for (int k = 0; k < 16; k++) {
        const int kk = k * 32 + lh * 8;
        bf16x8 bq;
        if (k < 8) bq = *reinterpret_cast<const bf16x8*>(&qh[pp * 256 + (kk ^ swz)]);
        else       bq = *reinterpret_cast<const bf16x8*>(&at[pp * 256 + ((kk - 256) ^ swz)]);
        #pragma unroll
        for (int i = 0; i < 16; i++) {
            bf16x8 ah = *reinterpret_cast<const bf16x8*>(&Ahi[(i * 16 + ln) * 512 + kk]);
            bf16x8 al = *reinterpret_cast<const bf16x8*>(&Alo[(i * 16 + ln) * 512 + kk]);
            yac[i] = __builtin_amdgcn_mfma_f32_16x16x32_bf16(ah, bq, yac[i], 0, 0, 0);
            yac[i] = __builtin_amdgcn_mfma_f32_16x16x32_bf16(al, bq, yac[i], 0, 0, 0);
        }
    }

    // ---- store y + BN partial sums (reduce over the 16 pixels sharing each o)
    const int obase = ((b * COUT) << 14) + hw0;
    #pragma unroll
    for (int i = 0; i < 16; i++) {
        #pragma unroll
        for (int r = 0; r < 4; r++) {
            int o = i * 16 + lh * 4 + r;
            float v = yac[i][r];
            out[obase + o * HWV + pp] = v;
            float pv = v, pq = v * v;
            pv += __shfl_xor(pv, 1); pq += __shfl_xor(pq, 1);
            pv += __shfl_xor(pv, 2); pq += __shfl_xor(pq, 2);
            pv += __shfl_xor(pv, 4); pq += __shfl_xor(pq, 4);
            pv += __shfl_xor(pv, 8); pq += __shfl_xor(pq, 8);
            if (ln == 0) { atomicAdd(&gsum[o], pv); atomicAdd(&gss[o], pq); }
        }
    }
}

// ---------------- k2: finalize BN affine params
__global__ void k2(const float* __restrict__ gsum, const float* __restrict__ gss,
                   const float* __restrict__ gamma, const float* __restrict__ beta,
                   float* __restrict__ params) {
    const int o = threadIdx.x;
    const float inv_n = 1.0f / (float)NPIX;
    float mean = gsum[o] * inv_n;
    float var  = gss[o] * inv_n - mean * mean;
    float sc   = gamma[o] / sqrtf(var + 1e-5f);
    params[o]       = sc;
    params[256 + o] = beta[o] - mean * sc;
}

// ---------------- k3: apply BN + ReLU in place on d_out
__global__ void k3(float* __restrict__ out, const float* __restrict__ params) {
    const int idx = blockIdx.x * 256 + threadIdx.x;   // float4 index
    const int o = (idx >> 12) & 255;
    f4* o4 = (f4*)out;
    f4 v = o4[idx];
    float sc = params[o], bi = params[256 + o];
    v[0] = fmaxf(fmaf(v[0], sc, bi), 0.0f);
    v[1] = fmaxf(fmaf(v[1], sc, bi), 0.0f);
    v[2] = fmaxf(fmaf(v[2], sc, bi), 0.0f);
    v[3] = fmaxf(fmaf(v[3], sc, bi), 0.0f);
    o4[idx] = v;
}

extern "C" void kernel_launch(void* const* d_in, const int* in_sizes, int n_in,
                              void* d_out, int out_size, void* d_ws, size_t ws_size,
                              hipStream_t stream) {
    const float* query   = (const float*)d_in[0];
    const float* t_items = (const float*)d_in[1];
    const float* w_out   = (const float*)d_in[2];
    const float* gamma   = (const float*)d_in[3];
    const float* beta    = (const float*)d_in[4];
    float* out = (float*)d_out;
    char* base = (char*)d_ws;

    // ws layout (bytes): Tbf 128K | Ahi 256K | Alo 256K | gsum 1K | gss 1K | params 2K
    u16*   Tbf    = (u16*)(base);
    u16*   Ahi    = (u16*)(base + 131072);
    u16*   Alo    = (u16*)(base + 393216);
    float* gsum   = (float*)(base + 655360);
    float* gss    = (float*)(base + 656384);
    float* params = (float*)(base + 657408);

    kM<<<256, 256, 0, stream>>>(w_out, t_items, Tbf, Ahi, Alo, gsum, gss);
    k1<<<NPIX / PT, 256, 0, stream>>>(query, Tbf, Ahi, Alo, out, gsum, gss);
    k2<<<1, 256, 0, stream>>>(gsum, gss, gamma, beta, params);
    k3<<<NPIX * COUT / 4 / 256, 256, 0, stream>>>(out, params);
}

// Round 8
// 499.203 us; speedup vs baseline: 2.9908x; 2.9908x over previous
//
#include <hip/hip_runtime.h>
#include <hip/hip_bf16.h>
#include <math.h>

// Problem constants
#define CC    256      // channels
#define RR    256      // token bank size
#define HWV   16384    // H*W
#define NPIX  131072   // B*H*W
#define COUT  256
#define PT    64       // pixels per block (k1)

typedef float f4 __attribute__((ext_vector_type(4)));
typedef float f32x4 __attribute__((ext_vector_type(4)));
typedef short bf16x8 __attribute__((ext_vector_type(8)));  // 8 bf16 = 4 VGPRs
typedef short s16x4 __attribute__((ext_vector_type(4)));   // 8B
typedef unsigned short u16;

__device__ __forceinline__ u16 f2bf(float x) {
    __hip_bfloat16 h = __float2bfloat16(x);      // RNE
    return *reinterpret_cast<u16*>(&h);
}
__device__ __forceinline__ float bf2f(u16 u) {
    __hip_bfloat16 h = *reinterpret_cast<__hip_bfloat16*>(&u);
    return __bfloat162float(h);
}

// ---------------- kM: precompute bf16 operand matrices + zero BN accumulators
__global__ void kM(const float* __restrict__ w_out, const float* __restrict__ t_items,
                   u16* __restrict__ Tbf, u16* __restrict__ Ahi, u16* __restrict__ Alo,
                   float* __restrict__ gsum, float* __restrict__ gss) {
    __shared__ float wl[CC];
    const int o = blockIdx.x;
    const int t = threadIdx.x;           // 256 threads
    if (t == 0) { gsum[o] = 0.0f; gss[o] = 0.0f; }
    wl[t] = w_out[o * 512 + 256 + t];    // W2 row o
    Tbf[o * 256 + t] = f2bf(t_items[o * 256 + t]);
    float w1 = w_out[o * 512 + t];
    u16 h1 = f2bf(w1);
    Ahi[o * 512 + t] = h1;
    Alo[o * 512 + t] = f2bf(w1 - bf2f(h1));
    __syncthreads();
    const f4* tr = (const f4*)(t_items + t * CC);
    float acc = 0.0f;
    #pragma unroll
    for (int c4 = 0; c4 < 64; c4++) {
        f4 v = tr[c4];
        acc = fmaf(wl[c4*4+0], v[0], acc);
        acc = fmaf(wl[c4*4+1], v[1], acc);
        acc = fmaf(wl[c4*4+2], v[2], acc);
        acc = fmaf(wl[c4*4+3], v[3], acc);
    }
    u16 h2 = f2bf(acc);
    Ahi[o * 512 + 256 + t] = h2;
    Alo[o * 512 + 256 + t] = f2bf(acc - bf2f(h2));
}

// ---------------- k1: MFMA-fused, re-tiled for A-reuse (R7 lesson):
// wave w owns ROW range [w*64, w*64+64) (4 MFMA row-tiles) x ALL 64 pixels (4 col-tiles).
// Per k-step: 4 A-frags + 4 B-frags feed 16 MFMAs (cue) / 8+4 frags -> 32 MFMAs (y).
// A-frags register-reused across 4 pixel-tiles -> loads/wave 656 -> 288, with
// 16-32 independent MFMAs between dependent loads (latency hiding via ILP).
// Softmax is now cross-wave (r split across waves): 3-barrier LDS max/sum exchange.
// MFMA 16x16x32_bf16: A lane holds A[l&15][(l>>4)*8+j]; B lane B[(l>>4)*8+j][l&15];
// C/D: col=lane&15, row=(lane>>4)*4+reg (m89-verified).
__global__ __launch_bounds__(256, 2)
void k1(const float* __restrict__ query, const u16* __restrict__ Tbf,
        const u16* __restrict__ Ahi, const u16* __restrict__ Alo,
        float* __restrict__ out, float* __restrict__ gsum, float* __restrict__ gss) {
    __shared__ u16 qh[PT * 256];    // qhatT [p][c], swizzled, 32KB
    __shared__ u16 at[PT * 256];    // attnT [p][r], swizzled, 32KB
    __shared__ float red[4][PT];    // cross-wave scratch (norms, smax, ssum)
    __shared__ float scl[PT];

    const int t    = threadIdx.x;
    const int l    = t & 63;
    const int w    = t >> 6;          // wave 0..3
    const int pix0 = blockIdx.x * PT;
    const int b    = pix0 >> 14;
    const int hw0  = pix0 & (HWV - 1);
    const int qbase = ((b * CC) << 14) + hw0;

    // ---- Pass A: per-pixel L2 norm; thread (w,l) loads channels [w*64,w*64+64) of pixel l
    const int p  = l;
    const int ch = w;
    float q[64];
    {
        float ss = 0.0f;
        #pragma unroll
        for (int j = 0; j < 64; j++) {
            q[j] = query[qbase + (ch * 64 + j) * HWV + p];
            ss = fmaf(q[j], q[j], ss);
        }
        red[ch][p] = ss;
    }
    __syncthreads();
    if (t < 64) {
        float tot = red[0][t] + red[1][t] + red[2][t] + red[3][t];
        scl[t] = 1.0f / fmaxf(sqrtf(tot), 1e-12f);
    }
    __syncthreads();
    // ---- Pass B: qhatT -> LDS as bf16, swizzled
    {
        float s = scl[p];
        #pragma unroll
        for (int g = 0; g < 8; g++) {
            u16 pk[8];
            #pragma unroll
            for (int i = 0; i < 8; i++) pk[i] = f2bf(q[g * 8 + i] * s);
            int c0 = ch * 64 + g * 8;
            int idx = p * 256 + (c0 ^ ((p & 7) << 3));
            *reinterpret_cast<bf16x8*>(&qh[idx]) = *reinterpret_cast<bf16x8*>(pk);
        }
    }
    __syncthreads();

    const int ln   = l & 15;          // col within 16-tile
    const int lh   = l >> 4;          // k-subblock / row-group
    const int swz  = (ln & 7) << 3;   // pixel-row swizzle (pt*16 doesn't affect &7)
    const int rowA = w * 64;          // wave's row range base (r or o)

    // ---- cue GEMM: acc[i][pt] = T[rowA+i*16..][.] @ qhatT[.][pt*16..]
    f32x4 acc[16];
    #pragma unroll
    for (int i = 0; i < 16; i++) acc[i] = f32x4{0.f, 0.f, 0.f, 0.f};
    #pragma unroll
    for (int k = 0; k < 8; k++) {
        const int c0 = k * 32 + lh * 8;
        bf16x8 bq[4];
        #pragma unroll
        for (int pt = 0; pt < 4; pt++)
            bq[pt] = *reinterpret_cast<const bf16x8*>(&qh[(pt * 16 + ln) * 256 + (c0 ^ swz)]);
        #pragma unroll
        for (int i = 0; i < 4; i++) {
            bf16x8 av = *reinterpret_cast<const bf16x8*>(&Tbf[(rowA + i * 16 + ln) * 256 + c0]);
            #pragma unroll
            for (int pt = 0; pt < 4; pt++)
                acc[i * 4 + pt] = __builtin_amdgcn_mfma_f32_16x16x32_bf16(av, bq[pt], acc[i * 4 + pt], 0, 0, 0);
        }
    }

    // ---- softmax over r (cross-wave: each wave holds 64 of 256 r per pixel)
    {
        // wave-local max per pixel-slot pt
        float mx[4];
        #pragma unroll
        for (int pt = 0; pt < 4; pt++) {
            float m = -1e30f;
            #pragma unroll
            for (int i = 0; i < 4; i++) {
                f32x4 v = acc[i * 4 + pt];
                m = fmaxf(m, fmaxf(fmaxf(v[0], v[1]), fmaxf(v[2], v[3])));
            }
            m = fmaxf(m, __shfl_xor(m, 16));
            m = fmaxf(m, __shfl_xor(m, 32));
            mx[pt] = m;
        }
        if (lh == 0) {
            #pragma unroll
            for (int pt = 0; pt < 4; pt++) red[w][pt * 16 + ln] = mx[pt];
        }
        __syncthreads();
        float gmx[4];
        #pragma unroll
        for (int pt = 0; pt < 4; pt++) {
            int pp = pt * 16 + ln;
            gmx[pt] = fmaxf(fmaxf(red[0][pp], red[1][pp]), fmaxf(red[2][pp], red[3][pp]));
        }
        __syncthreads();
        // exp + wave-local sum
        float sm[4];
        #pragma unroll
        for (int pt = 0; pt < 4; pt++) {
            float s = 0.0f;
            #pragma unroll
            for (int i = 0; i < 4; i++) {
                #pragma unroll
                for (int r = 0; r < 4; r++) {
                    float e = __expf(acc[i * 4 + pt][r] - gmx[pt]);
                    acc[i * 4 + pt][r] = e;
                    s += e;
                }
            }
            s += __shfl_xor(s, 16);
            s += __shfl_xor(s, 32);
            sm[pt] = s;
        }
        if (lh == 0) {
            #pragma unroll
            for (int pt = 0; pt < 4; pt++) red[w][pt * 16 + ln] = sm[pt];
        }
        __syncthreads();
        #pragma unroll
        for (int pt = 0; pt < 4; pt++) {
            int pp = pt * 16 + ln;
            float inv = 1.0f / (red[0][pp] + red[1][pp] + red[2][pp] + red[3][pp]);
            // attnT -> LDS bf16 (rows rowA..rowA+64 of each pixel)
            #pragma unroll
            for (int i = 0; i < 4; i++) {
                u16 pk[4];
                #pragma unroll
                for (int r = 0; r < 4; r++) pk[r] = f2bf(acc[i * 4 + pt][r] * inv);
                int r0 = rowA + i * 16 + lh * 4;
                *reinterpret_cast<s16x4*>(&at[pp * 256 + (r0 ^ swz)]) = *reinterpret_cast<s16x4*>(pk);
            }
        }
    }
    __syncthreads();    // at written by all waves, read by all waves below

    // ---- y GEMM: yac[i][pt], rows o=rowA+i*16.., K=512 = [qhat(256); attn(256)], hi+lo A
    f32x4 yac[16];
    #pragma unroll
    for (int i = 0; i < 16; i++) yac[i] = f32x4{0.f, 0.f, 0.f, 0.f};
    #pragma unroll
    for (int k = 0; k < 8; k++) {          // K-first-half: B = qhat
        const int kk = k * 32 + lh * 8;
        bf16x8 bq[4];
        #pragma unroll
        for (int pt = 0; pt < 4; pt++)
            bq[pt] = *reinterpret_cast<const bf16x8*>(&qh[(pt * 16 + ln) * 256 + (kk ^ swz)]);
        #pragma unroll
        for (int i = 0; i < 4; i++) {
            const int ar = (rowA + i * 16 + ln) * 512 + kk;
            bf16x8 ah = *reinterpret_cast<const bf16x8*>(&Ahi[ar]);
            bf16x8 al = *reinterpret_cast<const bf16x8*>(&Alo[ar]);
            #pragma unroll
            for (int pt = 0; pt < 4; pt++) {
                yac[i * 4 + pt] = __builtin_amdgcn_mfma_f32_16x16x32_bf16(ah, bq[pt], yac[i * 4 + pt], 0, 0, 0);
                yac[i * 4 + pt] = __builtin_amdgcn_mfma_f32_16x16x32_bf16(al, bq[pt], yac[i * 4 + pt], 0, 0, 0);
            }
        }
    }
    #pragma unroll
    for (int k = 0; k < 8; k++) {          // K-second-half: B = attn
        const int kk = k * 32 + lh * 8;
        bf16x8 bq[4];
        #pragma unroll
        for (int pt = 0; pt < 4; pt++)
            bq[pt] = *reinterpret_cast<const bf16x8*>(&at[(pt * 16 + ln) * 256 + (kk ^ swz)]);
        #pragma unroll
        for (int i = 0; i < 4; i++) {
            const int ar = (rowA + i * 16 + ln) * 512 + 256 + kk;
            bf16x8 ah = *reinterpret_cast<const bf16x8*>(&Ahi[ar]);
            bf16x8 al = *reinterpret_cast<const bf16x8*>(&Alo[ar]);
            #pragma unroll
            for (int pt = 0; pt < 4; pt++) {
                yac[i * 4 + pt] = __builtin_amdgcn_mfma_f32_16x16x32_bf16(ah, bq[pt], yac[i * 4 + pt], 0, 0, 0);
                yac[i * 4 + pt] = __builtin_amdgcn_mfma_f32_16x16x32_bf16(al, bq[pt], yac[i * 4 + pt], 0, 0, 0);
            }
        }
    }

    // ---- store y + BN partial sums (sum over this block's 64 pixels per o)
    const int obase = ((b * COUT) << 14) + hw0;
    #pragma unroll
    for (int i = 0; i < 4; i++) {
        #pragma unroll
        for (int r = 0; r < 4; r++) {
            const int o = rowA + i * 16 + lh * 4 + r;
            float pv = 0.0f, pq = 0.0f;
            #pragma unroll
            for (int pt = 0; pt < 4; pt++) {
                float v = yac[i * 4 + pt][r];
                out[obase + o * HWV + pt * 16 + ln] = v;
                pv += v;
                pq = fmaf(v, v, pq);
            }
            pv += __shfl_xor(pv, 1); pq += __shfl_xor(pq, 1);
            pv += __shfl_xor(pv, 2); pq += __shfl_xor(pq, 2);
            pv += __shfl_xor(pv, 4); pq += __shfl_xor(pq, 4);
            pv += __shfl_xor(pv, 8); pq += __shfl_xor(pq, 8);
            if (ln == 0) { atomicAdd(&gsum[o], pv); atomicAdd(&gss[o], pq); }
        }
    }
}

// ---------------- k2: finalize BN affine params
__global__ void k2(const float* __restrict__ gsum, const float* __restrict__ gss,
                   const float* __restrict__ gamma, const float* __restrict__ beta,
                   float* __restrict__ params) {
    const int o = threadIdx.x;
    const float inv_n = 1.0f / (float)NPIX;
    float mean = gsum[o] * inv_n;
    float var  = gss[o] * inv_n - mean * mean;
    float sc   = gamma[o] / sqrtf(var + 1e-5f);
    params[o]       = sc;
    params[256 + o] = beta[o] - mean * sc;
}

// ---------------- k3: apply BN + ReLU in place on d_out
__global__ void k3(float* __restrict__ out, const float* __restrict__ params) {
    const int idx = blockIdx.x * 256 + threadIdx.x;   // float4 index
    const int o = (idx >> 12) & 255;
    f4* o4 = (f4*)out;
    f4 v = o4[idx];
    float sc = params[o], bi = params[256 + o];
    v[0] = fmaxf(fmaf(v[0], sc, bi), 0.0f);
    v[1] = fmaxf(fmaf(v[1], sc, bi), 0.0f);
    v[2] = fmaxf(fmaf(v[2], sc, bi), 0.0f);
    v[3] = fmaxf(fmaf(v[3], sc, bi), 0.0f);
    o4[idx] = v;
}

extern "C" void kernel_launch(void* const* d_in, const int* in_sizes, int n_in,
                              void* d_out, int out_size, void* d_ws, size_t ws_size,
                              hipStream_t stream) {
    const float* query   = (const float*)d_in[0];
    const float* t_items = (const float*)d_in[1];
    const float* w_out   = (const float*)d_in[2];
    const float* gamma   = (const float*)d_in[3];
    const float* beta    = (const float*)d_in[4];
    float* out = (float*)d_out;
    char* base = (char*)d_ws;

    // ws layout (bytes): Tbf 128K | Ahi 256K | Alo 256K | gsum 1K | gss 1K | params 2K
    u16*   Tbf    = (u16*)(base);
    u16*   Ahi    = (u16*)(base + 131072);
    u16*   Alo    = (u16*)(base + 393216);
    float* gsum   = (float*)(base + 655360);
    float* gss    = (float*)(base + 656384);
    float* params = (float*)(base + 657408);

    kM<<<256, 256, 0, stream>>>(w_out, t_items, Tbf, Ahi, Alo, gsum, gss);
    k1<<<NPIX / PT, 256, 0, stream>>>(query, Tbf, Ahi, Alo, out, gsum, gss);
    k2<<<1, 256, 0, stream>>>(gsum, gss, gamma, beta, params);
    k3<<<NPIX * COUT / 4 / 256, 256, 0, stream>>>(out, params);
}

// Round 9
// 472.393 us; speedup vs baseline: 3.1605x; 1.0568x over previous
//
#include <hip/hip_runtime.h>
#include <hip/hip_bf16.h>
#include <math.h>

// Problem constants
#define CC    256      // channels
#define RR    256      // token bank size
#define HWV   16384    // H*W
#define NPIX  131072   // B*H*W
#define COUT  256
#define PT    64       // pixels per block (k1)

typedef float f4 __attribute__((ext_vector_type(4)));
typedef float f32x4 __attribute__((ext_vector_type(4)));
typedef short bf16x8 __attribute__((ext_vector_type(8)));  // 8 bf16 = 4 VGPRs
typedef short s16x4 __attribute__((ext_vector_type(4)));   // 8B
typedef unsigned short u16;

__device__ __forceinline__ u16 f2bf(float x) {
    __hip_bfloat16 h = __float2bfloat16(x);      // RNE
    return *reinterpret_cast<u16*>(&h);
}
__device__ __forceinline__ float bf2f(u16 u) {
    __hip_bfloat16 h = *reinterpret_cast<__hip_bfloat16*>(&u);
    return __bfloat162float(h);
}

// ---------------- kM: precompute bf16 operand matrices + zero BN accumulators
__global__ void kM(const float* __restrict__ w_out, const float* __restrict__ t_items,
                   u16* __restrict__ Tbf, u16* __restrict__ Ahi, u16* __restrict__ Alo,
                   float* __restrict__ gsum, float* __restrict__ gss) {
    __shared__ float wl[CC];
    const int o = blockIdx.x;
    const int t = threadIdx.x;           // 256 threads
    if (t == 0) { gsum[o] = 0.0f; gss[o] = 0.0f; }
    wl[t] = w_out[o * 512 + 256 + t];    // W2 row o
    Tbf[o * 256 + t] = f2bf(t_items[o * 256 + t]);
    float w1 = w_out[o * 512 + t];
    u16 h1 = f2bf(w1);
    Ahi[o * 512 + t] = h1;
    Alo[o * 512 + t] = f2bf(w1 - bf2f(h1));
    __syncthreads();
    const f4* tr = (const f4*)(t_items + t * CC);
    float acc = 0.0f;
    #pragma unroll
    for (int c4 = 0; c4 < 64; c4++) {
        f4 v = tr[c4];
        acc = fmaf(wl[c4*4+0], v[0], acc);
        acc = fmaf(wl[c4*4+1], v[1], acc);
        acc = fmaf(wl[c4*4+2], v[2], acc);
        acc = fmaf(wl[c4*4+3], v[3], acc);
    }
    u16 h2 = f2bf(acc);
    Ahi[o * 512 + 256 + t] = h2;
    Alo[o * 512 + 256 + t] = f2bf(acc - bf2f(h2));
}

// ---------------- k1: MFMA-fused; R8 lesson: software-pipeline the GEMM loops.
// Wave w owns rows [w*64,w*64+64) x all 64 pixels. R8 showed VGPR=96 => scheduler
// kept ~0 loads in flight (MfmaUtil 11%). Here: explicit double-buffered operand
// regs + "#pragma unroll 1" outer loop force ld(k+1) to issue a full MFMA-block
// (~160cy) before use; LDS caps occupancy at 2 blocks/CU so VGPRs<=256 are free.
// MFMA 16x16x32_bf16: A lane holds A[l&15][(l>>4)*8+j]; B lane B[(l>>4)*8+j][l&15];
// C/D: col=lane&15, row=(lane>>4)*4+reg (m89-verified).
__global__ __launch_bounds__(256, 2)
void k1(const float* __restrict__ query, const u16* __restrict__ Tbf,
        const u16* __restrict__ Ahi, const u16* __restrict__ Alo,
        float* __restrict__ out, float* __restrict__ gsum, float* __restrict__ gss) {
    __shared__ u16 qh[PT * 256];    // qhatT [p][c], swizzled, 32KB
    __shared__ u16 at[PT * 256];    // attnT [p][r], swizzled, 32KB
    __shared__ float red[4][PT];    // cross-wave scratch (norms, smax, ssum)
    __shared__ float scl[PT];

    const int t    = threadIdx.x;
    const int l    = t & 63;
    const int w    = t >> 6;          // wave 0..3
    const int pix0 = blockIdx.x * PT;
    const int b    = pix0 >> 14;
    const int hw0  = pix0 & (HWV - 1);
    const int qbase = ((b * CC) << 14) + hw0;

    // ---- Pass A: per-pixel L2 norm; thread (w,l) loads channels [w*64,w*64+64) of pixel l
    const int p  = l;
    const int ch = w;
    float q[64];
    {
        float ss = 0.0f;
        #pragma unroll
        for (int j = 0; j < 64; j++) {
            q[j] = query[qbase + (ch * 64 + j) * HWV + p];
            ss = fmaf(q[j], q[j], ss);
        }
        red[ch][p] = ss;
    }
    __syncthreads();
    if (t < 64) {
        float tot = red[0][t] + red[1][t] + red[2][t] + red[3][t];
        scl[t] = 1.0f / fmaxf(sqrtf(tot), 1e-12f);
    }
    __syncthreads();
    // ---- Pass B: qhatT -> LDS as bf16, swizzled
    {
        float s = scl[p];
        #pragma unroll
        for (int g = 0; g < 8; g++) {
            u16 pk[8];
            #pragma unroll
            for (int i = 0; i < 8; i++) pk[i] = f2bf(q[g * 8 + i] * s);
            int c0 = ch * 64 + g * 8;
            int idx = p * 256 + (c0 ^ ((p & 7) << 3));
            *reinterpret_cast<bf16x8*>(&qh[idx]) = *reinterpret_cast<bf16x8*>(pk);
        }
    }
    __syncthreads();

    const int ln   = l & 15;          // col within 16-tile
    const int lh   = l >> 4;          // k-subblock / row-group
    const int swz  = (ln & 7) << 3;   // pixel-row swizzle
    const int rowA = w * 64;          // wave's row range base (r or o)

    // ==== cue GEMM (software-pipelined): acc[i][pt] = T[rowA..] @ qhatT
    f32x4 acc[16];
    #pragma unroll
    for (int i = 0; i < 16; i++) acc[i] = f32x4{0.f, 0.f, 0.f, 0.f};

    auto ld_cue = [&](int k, bf16x8 (&bqv)[4], bf16x8 (&avv)[4]) {
        const int c0 = k * 32 + lh * 8;
        #pragma unroll
        for (int pt = 0; pt < 4; pt++)
            bqv[pt] = *reinterpret_cast<const bf16x8*>(&qh[(pt * 16 + ln) * 256 + (c0 ^ swz)]);
        #pragma unroll
        for (int i = 0; i < 4; i++)
            avv[i] = *reinterpret_cast<const bf16x8*>(&Tbf[(rowA + i * 16 + ln) * 256 + c0]);
    };
    auto mm_cue = [&](bf16x8 (&bqv)[4], bf16x8 (&avv)[4]) {
        #pragma unroll
        for (int i = 0; i < 4; i++) {
            #pragma unroll
            for (int pt = 0; pt < 4; pt++)
                acc[i * 4 + pt] = __builtin_amdgcn_mfma_f32_16x16x32_bf16(avv[i], bqv[pt], acc[i * 4 + pt], 0, 0, 0);
        }
    };
    {
        bf16x8 bqA[4], avA[4], bqB[4], avB[4];
        ld_cue(0, bqA, avA);
        #pragma unroll 1
        for (int kk = 0; kk < 8; kk += 2) {
            ld_cue(kk + 1, bqB, avB);            // issue next while A computes
            mm_cue(bqA, avA);
            if (kk + 2 < 8) ld_cue(kk + 2, bqA, avA);
            mm_cue(bqB, avB);
        }
    }

    // ---- softmax over r (cross-wave: each wave holds 64 of 256 r per pixel)
    {
        float mx[4];
        #pragma unroll
        for (int pt = 0; pt < 4; pt++) {
            float m = -1e30f;
            #pragma unroll
            for (int i = 0; i < 4; i++) {
                f32x4 v = acc[i * 4 + pt];
                m = fmaxf(m, fmaxf(fmaxf(v[0], v[1]), fmaxf(v[2], v[3])));
            }
            m = fmaxf(m, __shfl_xor(m, 16));
            m = fmaxf(m, __shfl_xor(m, 32));
            mx[pt] = m;
        }
        if (lh == 0) {
            #pragma unroll
            for (int pt = 0; pt < 4; pt++) red[w][pt * 16 + ln] = mx[pt];
        }
        __syncthreads();
        float gmx[4];
        #pragma unroll
        for (int pt = 0; pt < 4; pt++) {
            int pp = pt * 16 + ln;
            gmx[pt] = fmaxf(fmaxf(red[0][pp], red[1][pp]), fmaxf(red[2][pp], red[3][pp]));
        }
        __syncthreads();
        float sm[4];
        #pragma unroll
        for (int pt = 0; pt < 4; pt++) {
            float s = 0.0f;
            #pragma unroll
            for (int i = 0; i < 4; i++) {
                #pragma unroll
                for (int r = 0; r < 4; r++) {
                    float e = __expf(acc[i * 4 + pt][r] - gmx[pt]);
                    acc[i * 4 + pt][r] = e;
                    s += e;
                }
            }
            s += __shfl_xor(s, 16);
            s += __shfl_xor(s, 32);
            sm[pt] = s;
        }
        if (lh == 0) {
            #pragma unroll
            for (int pt = 0; pt < 4; pt++) red[w][pt * 16 + ln] = sm[pt];
        }
        __syncthreads();
        #pragma unroll
        for (int pt = 0; pt < 4; pt++) {
            int pp = pt * 16 + ln;
            float inv = 1.0f / (red[0][pp] + red[1][pp] + red[2][pp] + red[3][pp]);
            #pragma unroll
            for (int i = 0; i < 4; i++) {
                u16 pk[4];
                #pragma unroll
                for (int r = 0; r < 4; r++) pk[r] = f2bf(acc[i * 4 + pt][r] * inv);
                int r0 = rowA + i * 16 + lh * 4;
                *reinterpret_cast<s16x4*>(&at[pp * 256 + (r0 ^ swz)]) = *reinterpret_cast<s16x4*>(pk);
            }
        }
    }
    __syncthreads();    // at written by all waves, read by all waves below

    // ==== y GEMM (software-pipelined), K=512 = [qhat(256); attn(256)], hi+lo A
    f32x4 yac[16];
    #pragma unroll
    for (int i = 0; i < 16; i++) yac[i] = f32x4{0.f, 0.f, 0.f, 0.f};

    auto ld_y = [&](const u16* Bsrc, int k, int aoff,
                    bf16x8 (&bqv)[4], bf16x8 (&ahv)[4], bf16x8 (&alv)[4]) {
        const int kk = k * 32 + lh * 8;
        #pragma unroll
        for (int pt = 0; pt < 4; pt++)
            bqv[pt] = *reinterpret_cast<const bf16x8*>(&Bsrc[(pt * 16 + ln) * 256 + (kk ^ swz)]);
        #pragma unroll
        for (int i = 0; i < 4; i++) {
            const int ar = (rowA + i * 16 + ln) * 512 + aoff + kk;
            ahv[i] = *reinterpret_cast<const bf16x8*>(&Ahi[ar]);
            alv[i] = *reinterpret_cast<const bf16x8*>(&Alo[ar]);
        }
    };
    auto mm_y = [&](bf16x8 (&bqv)[4], bf16x8 (&ahv)[4], bf16x8 (&alv)[4]) {
        #pragma unroll
        for (int i = 0; i < 4; i++) {
            #pragma unroll
            for (int pt = 0; pt < 4; pt++) {
                yac[i * 4 + pt] = __builtin_amdgcn_mfma_f32_16x16x32_bf16(ahv[i], bqv[pt], yac[i * 4 + pt], 0, 0, 0);
                yac[i * 4 + pt] = __builtin_amdgcn_mfma_f32_16x16x32_bf16(alv[i], bqv[pt], yac[i * 4 + pt], 0, 0, 0);
            }
        }
    };
    {
        bf16x8 bqA[4], ahA[4], alA[4], bqB[4], ahB[4], alB[4];
        // half 1: B = qhat (aoff 0)
        ld_y(qh, 0, 0, bqA, ahA, alA);
        #pragma unroll 1
        for (int kk = 0; kk < 8; kk += 2) {
            ld_y(qh, kk + 1, 0, bqB, ahB, alB);
            mm_y(bqA, ahA, alA);
            if (kk + 2 < 8) ld_y(qh, kk + 2, 0, bqA, ahA, alA);
            mm_y(bqB, ahB, alB);
        }
        // half 2: B = attn (aoff 256)
        ld_y(at, 0, 256, bqA, ahA, alA);
        #pragma unroll 1
        for (int kk = 0; kk < 8; kk += 2) {
            ld_y(at, kk + 1, 256, bqB, ahB, alB);
            mm_y(bqA, ahA, alA);
            if (kk + 2 < 8) ld_y(at, kk + 2, 256, bqA, ahA, alA);
            mm_y(bqB, ahB, alB);
        }
    }

    // ---- store y + BN partial sums (sum over this block's 64 pixels per o)
    const int obase = ((b * COUT) << 14) + hw0;
    #pragma unroll
    for (int i = 0; i < 4; i++) {
        #pragma unroll
        for (int r = 0; r < 4; r++) {
            const int o = rowA + i * 16 + lh * 4 + r;
            float pv = 0.0f, pq = 0.0f;
            #pragma unroll
            for (int pt = 0; pt < 4; pt++) {
                float v = yac[i * 4 + pt][r];
                out[obase + o * HWV + pt * 16 + ln] = v;
                pv += v;
                pq = fmaf(v, v, pq);
            }
            pv += __shfl_xor(pv, 1); pq += __shfl_xor(pq, 1);
            pv += __shfl_xor(pv, 2); pq += __shfl_xor(pq, 2);
            pv += __shfl_xor(pv, 4); pq += __shfl_xor(pq, 4);
            pv += __shfl_xor(pv, 8); pq += __shfl_xor(pq, 8);
            if (ln == 0) { atomicAdd(&gsum[o], pv); atomicAdd(&gss[o], pq); }
        }
    }
}

// ---------------- k2: finalize BN affine params
__global__ void k2(const float* __restrict__ gsum, const float* __restrict__ gss,
                   const float* __restrict__ gamma, const float* __restrict__ beta,
                   float* __restrict__ params) {
    const int o = threadIdx.x;
    const float inv_n = 1.0f / (float)NPIX;
    float mean = gsum[o] * inv_n;
    float var  = gss[o] * inv_n - mean * mean;
    float sc   = gamma[o] / sqrtf(var + 1e-5f);
    params[o]       = sc;
    params[256 + o] = beta[o] - mean * sc;
}

// ---------------- k3: apply BN + ReLU in place on d_out
__global__ void k3(float* __restrict__ out, const float* __restrict__ params) {
    const int idx = blockIdx.x * 256 + threadIdx.x;   // float4 index
    const int o = (idx >> 12) & 255;
    f4* o4 = (f4*)out;
    f4 v = o4[idx];
    float sc = params[o], bi = params[256 + o];
    v[0] = fmaxf(fmaf(v[0], sc, bi), 0.0f);
    v[1] = fmaxf(fmaf(v[1], sc, bi), 0.0f);
    v[2] = fmaxf(fmaf(v[2], sc, bi), 0.0f);
    v[3] = fmaxf(fmaf(v[3], sc, bi), 0.0f);
    o4[idx] = v;
}

extern "C" void kernel_launch(void* const* d_in, const int* in_sizes, int n_in,
                              void* d_out, int out_size, void* d_ws, size_t ws_size,
                              hipStream_t stream) {
    const float* query   = (const float*)d_in[0];
    const float* t_items = (const float*)d_in[1];
    const float* w_out   = (const float*)d_in[2];
    const float* gamma   = (const float*)d_in[3];
    const float* beta    = (const float*)d_in[4];
    float* out = (float*)d_out;
    char* base = (char*)d_ws;

    // ws layout (bytes): Tbf 128K | Ahi 256K | Alo 256K | gsum 1K | gss 1K | params 2K
    u16*   Tbf    = (u16*)(base);
    u16*   Ahi    = (u16*)(base + 131072);
    u16*   Alo    = (u16*)(base + 393216);
    float* gsum   = (float*)(base + 655360);
    float* gss    = (float*)(base + 656384);
    float* params = (float*)(base + 657408);

    kM<<<256, 256, 0, stream>>>(w_out, t_items, Tbf, Ahi, Alo, gsum, gss);
    k1<<<NPIX / PT, 256, 0, stream>>>(query, Tbf, Ahi, Alo, out, gsum, gss);
    k2<<<1, 256, 0, stream>>>(gsum, gss, gamma, beta, params);
    k3<<<NPIX * COUT / 4 / 256, 256, 0, stream>>>(out, params);
}